// Round 9
// baseline (415.396 us; speedup 1.0000x reference)
//
#include <hip/hip_runtime.h>

#define N_NODES 100000
#define D_IN 128
#define D_OUT 256            // OUT_CH * HEADS
#define NBLK 256             // coarse-pass blocks (1/CU)
#define NBKT 256             // bucket array size (196 used)
#define BSH  9               // bucket = dst >> 9  (512 nodes / bucket)
#define BNODES 512
#define NBUCKETS ((N_NODES + BNODES - 1) / BNODES)   // 196
#define CAP  19456           // max edges/bucket staged in LDS (binB)
#define CAPC 12544           // max edges staged per scatter sub-chunk (chunk=12500)

typedef __attribute__((ext_vector_type(8))) short short8_t;  // 8 bf16
typedef __attribute__((ext_vector_type(4))) float f32x4;

__device__ inline unsigned short f2bf_rne(float f) {
    unsigned u = __float_as_uint(f);
    u += 0x7fffu + ((u >> 16) & 1u);
    return (unsigned short)(u >> 16);
}

// ---------------------------------------------------------------------------
// x (fp32) -> xb (bf16 as ushort)
// ---------------------------------------------------------------------------
__global__ __launch_bounds__(256) void convert_kernel(
    const float* __restrict__ x, ushort* __restrict__ xb, int n4)
{
    int i = blockIdx.x * 256 + threadIdx.x;
    if (i < n4) {
        float4 v = ((const float4*)x)[i];
        ushort4 r;
        r.x = f2bf_rne(v.x); r.y = f2bf_rne(v.y);
        r.z = f2bf_rne(v.z); r.w = f2bf_rne(v.w);
        ((ushort4*)xb)[i] = r;
    }
}

// ---------------------------------------------------------------------------
// W (fp32 [128][256]) -> wfrag: MFMA B-fragment order, bf16.
// frag index fi = ks*16+nt (ks: K-step of 32, nt: 16-col tile).
// lane l, elem e  <->  B[k][n], k = ks*32 + (l>>4)*8 + e, n = nt*16 + (l&15).
// ---------------------------------------------------------------------------
__global__ __launch_bounds__(256) void wfrag_kernel(
    const float* __restrict__ W, short8_t* __restrict__ wfrag)
{
    int tid  = blockIdx.x * 256 + threadIdx.x;   // 4096 frags total
    int lane = tid & 63;
    int fi   = tid >> 6;                          // 0..63
    int ks   = fi >> 4, nt = fi & 15;
    int k0   = ks * 32 + (lane >> 4) * 8;
    int col  = nt * 16 + (lane & 15);
    short8_t v;
    #pragma unroll
    for (int e = 0; e < 8; e++)
        v[e] = (short)f2bf_rne(W[(size_t)(k0 + e) * D_OUT + col]);
    wfrag[tid] = v;
}

// ---------------------------------------------------------------------------
// Coarse pass 1: per-block LDS histogram of 196 buckets
// ---------------------------------------------------------------------------
__global__ __launch_bounds__(256) void binA_hist(
    const int* __restrict__ dst, int* __restrict__ blockHist, int E, int chunk)
{
    __shared__ int h[NBKT];
    int b = blockIdx.x, t = threadIdx.x;
    h[t] = 0;
    __syncthreads();
    int e0 = b * chunk, e1 = min(e0 + chunk, E);
    for (int e = e0 + t; e < e1; e += 256)
        atomicAdd(&h[dst[e] >> BSH], 1);
    __syncthreads();
    blockHist[b * NBKT + t] = h[t];
}

// ---------------------------------------------------------------------------
// Coarse pass 2a: per-bucket exclusive scan over NBLK=256 blocks, in place;
// bucketTotal[bucket] = column sum.
// ---------------------------------------------------------------------------
__global__ __launch_bounds__(256) void binA_scan(
    int* __restrict__ blockHist, int* __restrict__ bucketTotal)
{
    __shared__ int wsum[4];
    int bucket = blockIdx.x;
    int t = threadIdx.x, lane = t & 63, w = t >> 6;
    int v = blockHist[t * NBKT + bucket];
    int s = v;
    #pragma unroll
    for (int d = 1; d < 64; d <<= 1) {
        int u = __shfl_up(s, d);
        if (lane >= d) s += u;
    }
    if (lane == 63) wsum[w] = s;
    __syncthreads();
    int wo = 0;
    for (int j = 0; j < w; j++) wo += wsum[j];
    blockHist[t * NBKT + bucket] = wo + s - v;
    if (t == 255) {
        int tot = 0;
        for (int j = 0; j < 4; j++) tot += wsum[j];
        bucketTotal[bucket] = tot;
    }
}

// ---------------------------------------------------------------------------
// Coarse pass 2b: exclusive scan of bucketTotal[256] -> bucketBase[256]
// ---------------------------------------------------------------------------
__global__ __launch_bounds__(256) void binA_scanbase(
    const int* __restrict__ bucketTotal, int* __restrict__ bucketBase)
{
    __shared__ int wsum[4];
    int t = threadIdx.x, lane = t & 63, w = t >> 6;
    int v = bucketTotal[t];
    int s = v;
    #pragma unroll
    for (int d = 1; d < 64; d <<= 1) {
        int u = __shfl_up(s, d);
        if (lane >= d) s += u;
    }
    if (lane == 63) wsum[w] = s;
    __syncthreads();
    int wo = 0;
    for (int j = 0; j < w; j++) wo += wsum[j];
    bucketBase[t] = wo + s - v;
}

// ---------------------------------------------------------------------------
// Coarse pass 3 (REWRITTEN): LDS-staged scatter with COALESCED global writes.
// Per sub-chunk: LDS histogram -> block scan -> LDS 4B scatter (cheap) ->
// per-bucket contiguous run copy to global (wave-strided). Replaces 3.2M
// random 4B global stores (measured ~250us across R5-R8 variants) with
// ~200B contiguous bursts.
// ---------------------------------------------------------------------------
__global__ __launch_bounds__(256) void binA_scatter(
    const int* __restrict__ src, const int* __restrict__ dst,
    const int* __restrict__ blockHist, const int* __restrict__ bucketBase,
    unsigned* __restrict__ pairs, int E, int chunk)
{
    __shared__ unsigned stage[CAPC];   // 49 KB
    __shared__ int cnt[NBKT];
    __shared__ int lofs[NBKT];
    __shared__ int rankl[NBKT];
    __shared__ int gcur[NBKT];
    __shared__ int wsum[4];

    int b = blockIdx.x, t = threadIdx.x, lane = t & 63, w = t >> 6;
    int e0 = b * chunk, e1 = min(e0 + chunk, E);

    gcur[t] = bucketBase[t] + blockHist[b * NBKT + t];
    __syncthreads();

    for (int c0 = e0; c0 < e1; c0 += CAPC) {
        int c1 = c0 + CAPC; if (c1 > e1) c1 = e1;

        cnt[t] = 0;
        __syncthreads();

        // phase 1: histogram this sub-chunk
        for (int e = c0 + t; e < c1; e += 256)
            atomicAdd(&cnt[dst[e] >> BSH], 1);
        __syncthreads();

        // phase 2: block-wide exclusive scan of cnt -> lofs
        {
            int v = cnt[t];
            int s = v;
            #pragma unroll
            for (int d = 1; d < 64; d <<= 1) {
                int u = __shfl_up(s, d);
                if (lane >= d) s += u;
            }
            if (lane == 63) wsum[w] = s;
            __syncthreads();
            int wo = 0;
            for (int j = 0; j < w; j++) wo += wsum[j];
            int excl = wo + s - v;
            lofs[t]  = excl;
            rankl[t] = excl;
        }
        __syncthreads();

        // phase 3: scatter packed pairs into LDS (4B LDS scatter = cheap)
        for (int e = c0 + t; e < c1; e += 256) {
            int d = dst[e];
            int bin = d >> BSH;
            int pos = atomicAdd(&rankl[bin], 1);
            stage[pos] = ((unsigned)(d & (BNODES - 1)) << 17) | (unsigned)src[e];
        }
        __syncthreads();

        // phase 4: coalesced write-out; wave w handles bins w, w+4, ...
        for (int bin = w; bin < NBKT; bin += 4) {
            int lo = lofs[bin], c = cnt[bin], g = gcur[bin];
            for (int i = lane; i < c; i += 64)
                pairs[g + i] = stage[lo + i];
        }
        __syncthreads();

        // advance global cursors
        gcur[t] += cnt[t];
        __syncthreads();
    }
}

// ---------------------------------------------------------------------------
// Fine pass: per-bucket LDS counting sort (512-node buckets, ~80 KB LDS).
// Stages bucket edges in LDS, builds per-node deg/offs, rewrites sorted src
// IN PLACE over pairs. 2 bins per thread in the scan.
// ---------------------------------------------------------------------------
__global__ __launch_bounds__(256) void binB_sort(
    unsigned* __restrict__ pairs, const int* __restrict__ bucketBase,
    int* __restrict__ offs_g, int* __restrict__ deg_g)
{
    __shared__ unsigned stage[CAP];    // 76 KB
    __shared__ int hist[BNODES];
    __shared__ int rank[BNODES];
    __shared__ int wsum[4];

    int b = blockIdx.x, t = threadIdx.x, lane = t & 63, w = t >> 6;
    int e0 = bucketBase[b], e1 = bucketBase[b + 1];
    int cnt = e1 - e0;
    if (cnt > CAP) cnt = CAP;   // statistically unreachable (mean+24 sigma)

    hist[t] = 0; hist[t + 256] = 0;
    __syncthreads();

    for (int i = t; i < cnt; i += 256) {
        unsigned p = pairs[e0 + i];
        stage[i] = p;
        atomicAdd(&hist[p >> 17], 1);
    }
    __syncthreads();

    // scan 512 bins, 2 per thread
    int a0 = hist[t * 2], a1 = hist[t * 2 + 1];
    int v = a0 + a1;
    int s = v;
    #pragma unroll
    for (int d = 1; d < 64; d <<= 1) {
        int u = __shfl_up(s, d);
        if (lane >= d) s += u;
    }
    if (lane == 63) wsum[w] = s;
    __syncthreads();
    int wo = 0;
    for (int j = 0; j < w; j++) wo += wsum[j];
    int excl = wo + s - v;

    rank[t * 2]     = excl;
    rank[t * 2 + 1] = excl + a0;
    int node = (b << BSH) + t * 2;
    if (node < N_NODES) {
        offs_g[node] = e0 + excl;
        deg_g[node]  = a0;
    }
    if (node + 1 < N_NODES) {
        offs_g[node + 1] = e0 + excl + a0;
        deg_g[node + 1]  = a1;
    }
    __syncthreads();

    for (int i = t; i < cnt; i += 256) {
        unsigned p = stage[i];
        int pos = atomicAdd(&rank[p >> 17], 1);
        pairs[e0 + pos] = p & 0x1FFFFu;
    }
}

// ---------------------------------------------------------------------------
// Fused gather-aggregate + MFMA linear (round-5-verified, verbatim).
// ---------------------------------------------------------------------------
template <bool USE_BF16>
__global__ __launch_bounds__(256) void fused_kernel(
    const float* __restrict__ x,
    const ushort* __restrict__ xb,
    const int* __restrict__ offs,
    const int* __restrict__ deg,
    const int* __restrict__ sorted_src,
    const short8_t* __restrict__ wfrag,
    const float* __restrict__ b,
    float* __restrict__ out)
{
    __shared__ __align__(16) ushort shb[16 * D_IN];   // 4 KB bf16 h, swizzled

    int n0   = blockIdx.x * 16;
    int t    = threadIdx.x;
    int lane = t & 63;
    int w    = t >> 6;

    for (int nn = 0; nn < 4; nn++) {
        int nl = w * 4 + nn;
        int n  = n0 + nl;
        int start = offs[n];
        int d     = deg[n];
        float accx = 0.0f, accy = 0.0f;
        for (int base = 0; base < d; base += 64) {
            int m = d - base; if (m > 64) m = 64;
            int id = (lane < m) ? sorted_src[start + base + lane] : 0;
            int j = 0;
            for (; j + 4 <= m; j += 4) {
                int s0 = __builtin_amdgcn_readlane(id, j);
                int s1 = __builtin_amdgcn_readlane(id, j + 1);
                int s2 = __builtin_amdgcn_readlane(id, j + 2);
                int s3 = __builtin_amdgcn_readlane(id, j + 3);
                if (USE_BF16) {
                    ushort2 u0 = ((const ushort2*)(xb + (size_t)s0 * D_IN))[lane];
                    ushort2 u1 = ((const ushort2*)(xb + (size_t)s1 * D_IN))[lane];
                    ushort2 u2 = ((const ushort2*)(xb + (size_t)s2 * D_IN))[lane];
                    ushort2 u3 = ((const ushort2*)(xb + (size_t)s3 * D_IN))[lane];
                    accx += __uint_as_float((unsigned)u0.x << 16)
                          + __uint_as_float((unsigned)u1.x << 16)
                          + __uint_as_float((unsigned)u2.x << 16)
                          + __uint_as_float((unsigned)u3.x << 16);
                    accy += __uint_as_float((unsigned)u0.y << 16)
                          + __uint_as_float((unsigned)u1.y << 16)
                          + __uint_as_float((unsigned)u2.y << 16)
                          + __uint_as_float((unsigned)u3.y << 16);
                } else {
                    float2 v0 = ((const float2*)(x + (size_t)s0 * D_IN))[lane];
                    float2 v1 = ((const float2*)(x + (size_t)s1 * D_IN))[lane];
                    float2 v2 = ((const float2*)(x + (size_t)s2 * D_IN))[lane];
                    float2 v3 = ((const float2*)(x + (size_t)s3 * D_IN))[lane];
                    accx += v0.x + v1.x + v2.x + v3.x;
                    accy += v0.y + v1.y + v2.y + v3.y;
                }
            }
            for (; j < m; j++) {
                int s0 = __builtin_amdgcn_readlane(id, j);
                if (USE_BF16) {
                    ushort2 u0 = ((const ushort2*)(xb + (size_t)s0 * D_IN))[lane];
                    accx += __uint_as_float((unsigned)u0.x << 16);
                    accy += __uint_as_float((unsigned)u0.y << 16);
                } else {
                    float2 v0 = ((const float2*)(x + (size_t)s0 * D_IN))[lane];
                    accx += v0.x; accy += v0.y;
                }
            }
        }
        float invc = 1.0f / ((float)d + 1e-8f);
        float2 xv = ((const float2*)(x + (size_t)n * D_IN))[lane];
        float hx = xv.x + accx * invc;
        float hy = xv.y + accy * invc;
        unsigned hp = ((unsigned)f2bf_rne(hy) << 16) | (unsigned)f2bf_rne(hx);
        unsigned byteoff = ((unsigned)(nl * 256 + lane * 4)) ^ (((unsigned)nl & 7u) << 4);
        *(unsigned*)((char*)shb + byteoff) = hp;
    }
    __syncthreads();

    // ---- MFMA epilogue ----
    const int r  = lane & 15;
    const int hi = lane >> 4;

    short8_t afrag[4];
    #pragma unroll
    for (int ks = 0; ks < 4; ks++) {
        unsigned aoff = ((unsigned)(r * 256 + ks * 64 + hi * 16)) ^ (((unsigned)r & 7u) << 4);
        afrag[ks] = *(const short8_t*)((const char*)shb + aoff);
    }

    f32x4 zero = {0.0f, 0.0f, 0.0f, 0.0f};
    f32x4 acc0 = zero, acc1 = zero, acc2 = zero, acc3 = zero;
    const int nt0 = w * 4;
    #pragma unroll
    for (int ks = 0; ks < 4; ks++) {
        short8_t b0 = wfrag[(ks * 16 + nt0    ) * 64 + lane];
        short8_t b1 = wfrag[(ks * 16 + nt0 + 1) * 64 + lane];
        short8_t b2 = wfrag[(ks * 16 + nt0 + 2) * 64 + lane];
        short8_t b3 = wfrag[(ks * 16 + nt0 + 3) * 64 + lane];
        acc0 = __builtin_amdgcn_mfma_f32_16x16x32_bf16(afrag[ks], b0, acc0, 0, 0, 0);
        acc1 = __builtin_amdgcn_mfma_f32_16x16x32_bf16(afrag[ks], b1, acc1, 0, 0, 0);
        acc2 = __builtin_amdgcn_mfma_f32_16x16x32_bf16(afrag[ks], b2, acc2, 0, 0, 0);
        acc3 = __builtin_amdgcn_mfma_f32_16x16x32_bf16(afrag[ks], b3, acc3, 0, 0, 0);
    }

    #pragma unroll
    for (int nt = 0; nt < 4; nt++) {
        f32x4 a = (nt == 0) ? acc0 : (nt == 1) ? acc1 : (nt == 2) ? acc2 : acc3;
        int col = (nt0 + nt) * 16 + r;
        float bias = b[col];
        #pragma unroll
        for (int reg = 0; reg < 4; reg++) {
            int node = n0 + hi * 4 + reg;
            out[(size_t)node * D_OUT + col] = a[reg] + bias;
        }
    }
}

extern "C" void kernel_launch(void* const* d_in, const int* in_sizes, int n_in,
                              void* d_out, int out_size, void* d_ws, size_t ws_size,
                              hipStream_t stream)
{
    const float* x  = (const float*)d_in[0];
    const int*   ei = (const int*)d_in[1];   // [2,E] int32: row0=src, row1=dst
    const float* W  = (const float*)d_in[2];
    const float* b  = (const float*)d_in[3];
    float*       out = (float*)d_out;

    const int E = in_sizes[1] / 2;
    const int* src = ei;
    const int* dst = ei + E;
    const int chunk = (E + NBLK - 1) / NBLK;

    const size_t xb_bytes   = (size_t)N_NODES * D_IN * 2;     // 25.6 MB
    const size_t pairs_b    = (size_t)E * 4;                  // 12.8 MB
    const size_t bh_b       = (size_t)NBLK * NBKT * 4;        // 256 KB
    const size_t small_b    = (size_t)NBKT * 4;               // 1 KB each
    const size_t nodes_b    = (size_t)N_NODES * 4;            // 400 KB each
    const size_t wf_b       = (size_t)4096 * 16;              // 64 KB
    const size_t need_bf16  = xb_bytes + pairs_b + bh_b + 2 * small_b
                            + 2 * nodes_b + wf_b;             // ~39.5 MB
    const bool use_bf16 = (ws_size >= need_bf16);

    char* p = (char*)d_ws;
    ushort* xb = nullptr;
    if (use_bf16) { xb = (ushort*)p; p += xb_bytes; }
    unsigned* pairs  = (unsigned*)p;  p += pairs_b;
    int* blockHist   = (int*)p;       p += bh_b;
    int* bucketTotal = (int*)p;       p += small_b;
    int* bucketBase  = (int*)p;       p += small_b;
    int* offs        = (int*)p;       p += nodes_b;
    int* deg         = (int*)p;       p += nodes_b;
    short8_t* wfrag  = (short8_t*)p;

    if (use_bf16) {
        int n4 = N_NODES * D_IN / 4;
        convert_kernel<<<dim3((n4 + 255) / 256), dim3(256), 0, stream>>>(x, xb, n4);
    }
    wfrag_kernel<<<dim3(16), dim3(256), 0, stream>>>(W, wfrag);

    binA_hist    <<<dim3(NBLK), dim3(256), 0, stream>>>(dst, blockHist, E, chunk);
    binA_scan    <<<dim3(NBKT), dim3(256), 0, stream>>>(blockHist, bucketTotal);
    binA_scanbase<<<dim3(1),    dim3(256), 0, stream>>>(bucketTotal, bucketBase);
    binA_scatter <<<dim3(NBLK), dim3(256), 0, stream>>>(
        src, dst, blockHist, bucketBase, pairs, E, chunk);
    binB_sort    <<<dim3(NBUCKETS), dim3(256), 0, stream>>>(
        pairs, bucketBase, offs, deg);

    if (use_bf16)
        fused_kernel<true><<<dim3(N_NODES / 16), dim3(256), 0, stream>>>(
            x, xb, offs, deg, (const int*)pairs, wfrag, b, out);
    else
        fused_kernel<false><<<dim3(N_NODES / 16), dim3(256), 0, stream>>>(
            x, xb, offs, deg, (const int*)pairs, wfrag, b, out);
}

// Round 11
// 350.077 us; speedup vs baseline: 1.1866x; 1.1866x over previous
//
#include <hip/hip_runtime.h>

#define N_NODES 100000
#define D_IN 128
#define D_OUT 256            // OUT_CH * HEADS
#define NBLK 256             // hist/scatter blocks (1/CU)
#define NBKT 256             // bucket array size (196 used)
#define BSH  9               // bucket = dst >> 9  (512 nodes / bucket)
#define BNODES 512
#define NBUCKETS ((N_NODES + BNODES - 1) / BNODES)   // 196
#define CAP  19456           // max edges/bucket staged in LDS (binB)
#define CAPC 12544           // max edges staged per scatter sub-chunk
#define N4   (N_NODES * D_IN / 4)          // 3,200,000 float4 elems
#define CONV_BLKS ((N4 + 4095) / 4096)     // 782
#define WF_BLK0 (NBLK + CONV_BLKS)
#define K1_GRID (WF_BLK0 + 4)

typedef __attribute__((ext_vector_type(8))) short short8_t;  // 8 bf16
typedef __attribute__((ext_vector_type(4))) float f32x4;

__device__ inline unsigned short f2bf_rne(float f) {
    unsigned u = __float_as_uint(f);
    u += 0x7fffu + ((u >> 16) & 1u);
    return (unsigned short)(u >> 16);
}

// ---------------------------------------------------------------------------
// K1: convert || wfrag || hist fused into one launch (role by blockIdx).
// All roles are mutually independent; no cross-role sync.
// 1024 threads/block (16 waves) for TLP on the hist role.
// ---------------------------------------------------------------------------
__global__ __launch_bounds__(1024) void pre_kernel(
    const float* __restrict__ x, ushort* __restrict__ xb,
    const float* __restrict__ W, short8_t* __restrict__ wfrag,
    const int* __restrict__ dst, int* __restrict__ blockHist,
    int E, int chunk, int do_conv)
{
    __shared__ int h[NBKT];
    int bid = blockIdx.x, t = threadIdx.x;

    if (bid < NBLK) {
        // ---- hist role ----
        if (t < NBKT) h[t] = 0;
        __syncthreads();
        int e0 = bid * chunk, e1 = min(e0 + chunk, E);
        for (int e = e0 + t; e < e1; e += 1024)
            atomicAdd(&h[dst[e] >> BSH], 1);
        __syncthreads();
        if (t < NBKT) blockHist[bid * NBKT + t] = h[t];
    } else if (bid < WF_BLK0) {
        // ---- convert role: 4 float4 elems per thread ----
        if (!do_conv) return;
        int base = (bid - NBLK) * 4096 + t;
        #pragma unroll
        for (int k = 0; k < 4; k++) {
            int i = base + k * 1024;
            if (i < N4) {
                float4 v = ((const float4*)x)[i];
                ushort4 r;
                r.x = f2bf_rne(v.x); r.y = f2bf_rne(v.y);
                r.z = f2bf_rne(v.z); r.w = f2bf_rne(v.w);
                ((ushort4*)xb)[i] = r;
            }
        }
    } else {
        // ---- wfrag role: W -> MFMA B-fragment order, bf16 ----
        int tid = (bid - WF_BLK0) * 1024 + t;     // 4096 frags
        if (tid < 4096) {
            int lane = tid & 63;
            int fi   = tid >> 6;
            int ks = fi >> 4, nt = fi & 15;
            int k0 = ks * 32 + (lane >> 4) * 8;
            int col = nt * 16 + (lane & 15);
            short8_t v;
            #pragma unroll
            for (int e = 0; e < 8; e++)
                v[e] = (short)f2bf_rne(W[(size_t)(k0 + e) * D_OUT + col]);
            wfrag[tid] = v;
        }
    }
}

// ---------------------------------------------------------------------------
// K2: per-bucket exclusive scan over NBLK=256 blocks, in place;
// bucketTotal[bucket] = column sum.  (R8-proven, unchanged)
// ---------------------------------------------------------------------------
__global__ __launch_bounds__(256) void binA_scan(
    int* __restrict__ blockHist, int* __restrict__ bucketTotal)
{
    __shared__ int wsum[4];
    int bucket = blockIdx.x;
    int t = threadIdx.x, lane = t & 63, w = t >> 6;
    int v = blockHist[t * NBKT + bucket];
    int s = v;
    #pragma unroll
    for (int d = 1; d < 64; d <<= 1) {
        int u = __shfl_up(s, d);
        if (lane >= d) s += u;
    }
    if (lane == 63) wsum[w] = s;
    __syncthreads();
    int wo = 0;
    for (int j = 0; j < w; j++) wo += wsum[j];
    blockHist[t * NBKT + bucket] = wo + s - v;
    if (t == 255) {
        int tot = 0;
        for (int j = 0; j < 4; j++) tot += wsum[j];
        bucketTotal[bucket] = tot;
    }
}

// ---------------------------------------------------------------------------
// K3: LDS-staged scatter (R9 structure), 1024 threads. bucketBase is
// re-derived in-LDS from bucketTotal (1KB scan) — kills the scanbase launch.
// ---------------------------------------------------------------------------
__global__ __launch_bounds__(1024) void binA_scatter(
    const int* __restrict__ src, const int* __restrict__ dst,
    const int* __restrict__ blockHist, const int* __restrict__ bucketTotal,
    unsigned* __restrict__ pairs, int E, int chunk)
{
    __shared__ unsigned stage[CAPC];   // 49 KB
    __shared__ int cnt[NBKT], lofs[NBKT], rankl[NBKT], gcur[NBKT];
    __shared__ int wsum[16];

    int b = blockIdx.x, t = threadIdx.x, lane = t & 63, w = t >> 6;
    int e0 = b * chunk, e1 = min(e0 + chunk, E);

    // derive bucketBase + per-block cursor (waves 0-3 scan 256 bins)
    int sv = 0, ss = 0;
    if (t < NBKT) {
        sv = bucketTotal[t]; ss = sv;
        #pragma unroll
        for (int d = 1; d < 64; d <<= 1) {
            int u = __shfl_up(ss, d);
            if (lane >= d) ss += u;
        }
        if (lane == 63) wsum[w] = ss;
    }
    __syncthreads();
    if (t < NBKT) {
        int wo = 0;
        for (int j = 0; j < w; j++) wo += wsum[j];
        gcur[t] = (wo + ss - sv) + blockHist[b * NBKT + t];
    }
    __syncthreads();

    for (int c0 = e0; c0 < e1; c0 += CAPC) {
        int c1 = c0 + CAPC; if (c1 > e1) c1 = e1;

        if (t < NBKT) cnt[t] = 0;
        __syncthreads();

        for (int e = c0 + t; e < c1; e += 1024)
            atomicAdd(&cnt[dst[e] >> BSH], 1);
        __syncthreads();

        int v2 = 0, s2 = 0;
        if (t < NBKT) {
            v2 = cnt[t]; s2 = v2;
            #pragma unroll
            for (int d = 1; d < 64; d <<= 1) {
                int u = __shfl_up(s2, d);
                if (lane >= d) s2 += u;
            }
            if (lane == 63) wsum[w] = s2;
        }
        __syncthreads();
        if (t < NBKT) {
            int wo = 0;
            for (int j = 0; j < w; j++) wo += wsum[j];
            int excl = wo + s2 - v2;
            lofs[t]  = excl;
            rankl[t] = excl;
        }
        __syncthreads();

        for (int e = c0 + t; e < c1; e += 1024) {
            int d = dst[e];
            int bin = d >> BSH;
            int pos = atomicAdd(&rankl[bin], 1);
            stage[pos] = ((unsigned)(d & (BNODES - 1)) << 17) | (unsigned)src[e];
        }
        __syncthreads();

        // coalesced write-out; wave w handles bins w, w+16, ...
        for (int bin = w; bin < NBKT; bin += 16) {
            int lo = lofs[bin], c = cnt[bin], g = gcur[bin];
            for (int i = lane; i < c; i += 64)
                pairs[g + i] = stage[lo + i];
        }
        __syncthreads();

        if (t < NBKT) gcur[t] += cnt[t];
        __syncthreads();
    }
}

// ---------------------------------------------------------------------------
// K4: per-bucket LDS counting sort, 1024 threads (16 waves). e0/cnt derived
// in-LDS from bucketTotal. Writes offs/deg, rewrites sorted src over pairs.
// ---------------------------------------------------------------------------
__global__ __launch_bounds__(1024) void binB_sort(
    unsigned* __restrict__ pairs, const int* __restrict__ bucketTotal,
    int* __restrict__ offs_g, int* __restrict__ deg_g)
{
    __shared__ unsigned stage[CAP];    // 76 KB
    __shared__ int hist[BNODES];
    __shared__ int rank[BNODES];
    __shared__ int wsum[16];
    __shared__ int ebase[2];

    int b = blockIdx.x, t = threadIdx.x, lane = t & 63, w = t >> 6;

    // derive e0 (prefix of bucketTotal) and cnt (waves 0-3 scan 256 bins)
    int sv = 0, ss = 0;
    if (t < NBKT) {
        sv = bucketTotal[t]; ss = sv;
        #pragma unroll
        for (int d = 1; d < 64; d <<= 1) {
            int u = __shfl_up(ss, d);
            if (lane >= d) ss += u;
        }
        if (lane == 63) wsum[w] = ss;
    }
    __syncthreads();
    if (t < NBKT) {
        int wo = 0;
        for (int j = 0; j < w; j++) wo += wsum[j];
        if (t == b) { ebase[0] = wo + ss - sv; ebase[1] = sv; }
    }
    __syncthreads();
    const int e0 = ebase[0];
    int cnt = ebase[1];
    if (cnt > CAP) cnt = CAP;   // statistically unreachable

    if (t < BNODES) hist[t] = 0;
    __syncthreads();

    for (int i = t; i < cnt; i += 1024) {
        unsigned p = pairs[e0 + i];
        stage[i] = p;
        atomicAdd(&hist[p >> 17], 1);
    }
    __syncthreads();

    // scan 512 bins (waves 0-7)
    int v2 = 0, s2 = 0;
    if (t < BNODES) {
        v2 = hist[t]; s2 = v2;
        #pragma unroll
        for (int d = 1; d < 64; d <<= 1) {
            int u = __shfl_up(s2, d);
            if (lane >= d) s2 += u;
        }
        if (lane == 63) wsum[w] = s2;
    }
    __syncthreads();
    if (t < BNODES) {
        int wo = 0;
        for (int j = 0; j < w; j++) wo += wsum[j];
        int excl = wo + s2 - v2;
        rank[t] = excl;
        int node = (b << BSH) + t;
        if (node < N_NODES) {
            offs_g[node] = e0 + excl;
            deg_g[node]  = v2;
        }
    }
    __syncthreads();

    for (int i = t; i < cnt; i += 1024) {
        unsigned p = stage[i];
        int pos = atomicAdd(&rank[p >> 17], 1);
        pairs[e0 + pos] = p & 0x1FFFFu;
    }
}

// ---------------------------------------------------------------------------
// K5: fused gather-aggregate + MFMA linear (round-5-verified, verbatim).
// ---------------------------------------------------------------------------
template <bool USE_BF16>
__global__ __launch_bounds__(256) void fused_kernel(
    const float* __restrict__ x,
    const ushort* __restrict__ xb,
    const int* __restrict__ offs,
    const int* __restrict__ deg,
    const int* __restrict__ sorted_src,
    const short8_t* __restrict__ wfrag,
    const float* __restrict__ b,
    float* __restrict__ out)
{
    __shared__ __align__(16) ushort shb[16 * D_IN];   // 4 KB bf16 h, swizzled

    int n0   = blockIdx.x * 16;
    int t    = threadIdx.x;
    int lane = t & 63;
    int w    = t >> 6;

    for (int nn = 0; nn < 4; nn++) {
        int nl = w * 4 + nn;
        int n  = n0 + nl;
        int start = offs[n];
        int d     = deg[n];
        float accx = 0.0f, accy = 0.0f;
        for (int base = 0; base < d; base += 64) {
            int m = d - base; if (m > 64) m = 64;
            int id = (lane < m) ? sorted_src[start + base + lane] : 0;
            int j = 0;
            for (; j + 4 <= m; j += 4) {
                int s0 = __builtin_amdgcn_readlane(id, j);
                int s1 = __builtin_amdgcn_readlane(id, j + 1);
                int s2 = __builtin_amdgcn_readlane(id, j + 2);
                int s3 = __builtin_amdgcn_readlane(id, j + 3);
                if (USE_BF16) {
                    ushort2 u0 = ((const ushort2*)(xb + (size_t)s0 * D_IN))[lane];
                    ushort2 u1 = ((const ushort2*)(xb + (size_t)s1 * D_IN))[lane];
                    ushort2 u2 = ((const ushort2*)(xb + (size_t)s2 * D_IN))[lane];
                    ushort2 u3 = ((const ushort2*)(xb + (size_t)s3 * D_IN))[lane];
                    accx += __uint_as_float((unsigned)u0.x << 16)
                          + __uint_as_float((unsigned)u1.x << 16)
                          + __uint_as_float((unsigned)u2.x << 16)
                          + __uint_as_float((unsigned)u3.x << 16);
                    accy += __uint_as_float((unsigned)u0.y << 16)
                          + __uint_as_float((unsigned)u1.y << 16)
                          + __uint_as_float((unsigned)u2.y << 16)
                          + __uint_as_float((unsigned)u3.y << 16);
                } else {
                    float2 v0 = ((const float2*)(x + (size_t)s0 * D_IN))[lane];
                    float2 v1 = ((const float2*)(x + (size_t)s1 * D_IN))[lane];
                    float2 v2 = ((const float2*)(x + (size_t)s2 * D_IN))[lane];
                    float2 v3 = ((const float2*)(x + (size_t)s3 * D_IN))[lane];
                    accx += v0.x + v1.x + v2.x + v3.x;
                    accy += v0.y + v1.y + v2.y + v3.y;
                }
            }
            for (; j < m; j++) {
                int s0 = __builtin_amdgcn_readlane(id, j);
                if (USE_BF16) {
                    ushort2 u0 = ((const ushort2*)(xb + (size_t)s0 * D_IN))[lane];
                    accx += __uint_as_float((unsigned)u0.x << 16);
                    accy += __uint_as_float((unsigned)u0.y << 16);
                } else {
                    float2 v0 = ((const float2*)(x + (size_t)s0 * D_IN))[lane];
                    accx += v0.x; accy += v0.y;
                }
            }
        }
        float invc = 1.0f / ((float)d + 1e-8f);
        float2 xv = ((const float2*)(x + (size_t)n * D_IN))[lane];
        float hx = xv.x + accx * invc;
        float hy = xv.y + accy * invc;
        unsigned hp = ((unsigned)f2bf_rne(hy) << 16) | (unsigned)f2bf_rne(hx);
        unsigned byteoff = ((unsigned)(nl * 256 + lane * 4)) ^ (((unsigned)nl & 7u) << 4);
        *(unsigned*)((char*)shb + byteoff) = hp;
    }
    __syncthreads();

    // ---- MFMA epilogue ----
    const int r  = lane & 15;
    const int hi = lane >> 4;

    short8_t afrag[4];
    #pragma unroll
    for (int ks = 0; ks < 4; ks++) {
        unsigned aoff = ((unsigned)(r * 256 + ks * 64 + hi * 16)) ^ (((unsigned)r & 7u) << 4);
        afrag[ks] = *(const short8_t*)((const char*)shb + aoff);
    }

    f32x4 zero = {0.0f, 0.0f, 0.0f, 0.0f};
    f32x4 acc0 = zero, acc1 = zero, acc2 = zero, acc3 = zero;
    const int nt0 = w * 4;
    #pragma unroll
    for (int ks = 0; ks < 4; ks++) {
        short8_t b0 = wfrag[(ks * 16 + nt0    ) * 64 + lane];
        short8_t b1 = wfrag[(ks * 16 + nt0 + 1) * 64 + lane];
        short8_t b2 = wfrag[(ks * 16 + nt0 + 2) * 64 + lane];
        short8_t b3 = wfrag[(ks * 16 + nt0 + 3) * 64 + lane];
        acc0 = __builtin_amdgcn_mfma_f32_16x16x32_bf16(afrag[ks], b0, acc0, 0, 0, 0);
        acc1 = __builtin_amdgcn_mfma_f32_16x16x32_bf16(afrag[ks], b1, acc1, 0, 0, 0);
        acc2 = __builtin_amdgcn_mfma_f32_16x16x32_bf16(afrag[ks], b2, acc2, 0, 0, 0);
        acc3 = __builtin_amdgcn_mfma_f32_16x16x32_bf16(afrag[ks], b3, acc3, 0, 0, 0);
    }

    #pragma unroll
    for (int nt = 0; nt < 4; nt++) {
        f32x4 a = (nt == 0) ? acc0 : (nt == 1) ? acc1 : (nt == 2) ? acc2 : acc3;
        int col = (nt0 + nt) * 16 + r;
        float bias = b[col];
        #pragma unroll
        for (int reg = 0; reg < 4; reg++) {
            int node = n0 + hi * 4 + reg;
            out[(size_t)node * D_OUT + col] = a[reg] + bias;
        }
    }
}

extern "C" void kernel_launch(void* const* d_in, const int* in_sizes, int n_in,
                              void* d_out, int out_size, void* d_ws, size_t ws_size,
                              hipStream_t stream)
{
    const float* x  = (const float*)d_in[0];
    const int*   ei = (const int*)d_in[1];   // [2,E] int32: row0=src, row1=dst
    const float* W  = (const float*)d_in[2];
    const float* b  = (const float*)d_in[3];
    float*       out = (float*)d_out;

    const int E = in_sizes[1] / 2;
    const int* src = ei;
    const int* dst = ei + E;
    const int chunk = (E + NBLK - 1) / NBLK;

    const size_t xb_bytes   = (size_t)N_NODES * D_IN * 2;     // 25.6 MB
    const size_t pairs_b    = (size_t)E * 4;                  // 12.8 MB
    const size_t bh_b       = (size_t)NBLK * NBKT * 4;        // 256 KB
    const size_t small_b    = (size_t)NBKT * 4;               // 1 KB
    const size_t nodes_b    = (size_t)N_NODES * 4;            // 400 KB each
    const size_t wf_b       = (size_t)4096 * 16;              // 64 KB
    const size_t need_bf16  = xb_bytes + pairs_b + bh_b + small_b
                            + 2 * nodes_b + wf_b;
    const bool use_bf16 = (ws_size >= need_bf16);

    char* p = (char*)d_ws;
    ushort* xb = nullptr;
    if (use_bf16) { xb = (ushort*)p; p += xb_bytes; }
    unsigned* pairs  = (unsigned*)p;  p += pairs_b;
    int* blockHist   = (int*)p;       p += bh_b;
    int* bucketTotal = (int*)p;       p += small_b;
    int* offs        = (int*)p;       p += nodes_b;
    int* deg         = (int*)p;       p += nodes_b;
    short8_t* wfrag  = (short8_t*)p;

    pre_kernel  <<<dim3(K1_GRID), dim3(1024), 0, stream>>>(
        x, xb, W, wfrag, dst, blockHist, E, chunk, use_bf16 ? 1 : 0);
    binA_scan   <<<dim3(NBKT), dim3(256), 0, stream>>>(blockHist, bucketTotal);
    binA_scatter<<<dim3(NBLK), dim3(1024), 0, stream>>>(
        src, dst, blockHist, bucketTotal, pairs, E, chunk);
    binB_sort   <<<dim3(NBUCKETS), dim3(1024), 0, stream>>>(
        pairs, bucketTotal, offs, deg);

    if (use_bf16)
        fused_kernel<true><<<dim3(N_NODES / 16), dim3(256), 0, stream>>>(
            x, xb, offs, deg, (const int*)pairs, wfrag, b, out);
    else
        fused_kernel<false><<<dim3(N_NODES / 16), dim3(256), 0, stream>>>(
            x, xb, offs, deg, (const int*)pairs, wfrag, b, out);
}